// Round 1
// baseline (116.983 us; speedup 1.0000x reference)
//
#include <hip/hip_runtime.h>

#define B_ 8192
#define P_ 100
#define L_ 8
#define D_ 768
#define K_ 5
#define H_ 4
#define HD_ 192
#define S_ 40            // K_*L_
#define MPAD 896         // 800 padded to 7*128 (kv rows / score cols)
#define PPAD 128         // P_ padded

typedef unsigned short u16;
typedef unsigned char u8;
typedef __bf16 bf16x8 __attribute__((ext_vector_type(8)));
typedef float f32x4 __attribute__((ext_vector_type(4)));
typedef float f32x2 __attribute__((ext_vector_type(2)));

__device__ __forceinline__ u16 f2bf(float f) {
  __bf16 h = (__bf16)f;
  return __builtin_bit_cast(unsigned short, h);
}
__device__ __forceinline__ float bf2f(u16 u) {
  unsigned int v = ((unsigned int)u) << 16;
  return __builtin_bit_cast(float, v);
}
__device__ __forceinline__ float bflo(unsigned int u) {
  return __builtin_bit_cast(float, u << 16);
}
__device__ __forceinline__ float bfhi(unsigned int u) {
  return __builtin_bit_cast(float, u & 0xffff0000u);
}
__device__ __forceinline__ u8 f2fp8(float v) {
  const int p = __builtin_amdgcn_cvt_pk_fp8_f32(v, v, 0, false);
  return (u8)(p & 0xff);
}
__device__ __forceinline__ void gload16(const void* g, void* l) {
  __builtin_amdgcn_global_load_lds(
      (const __attribute__((address_space(1))) void*)g,
      (__attribute__((address_space(3))) void*)l, 16, 0, 0);
}
__device__ __forceinline__ void ldsbar() {
  asm volatile("s_waitcnt lgkmcnt(0)" ::: "memory");
  __builtin_amdgcn_s_barrier();
}

// ================= prep mega-kernel =================
#define NB_CASTX 6144
#define NB_TRANS 144
#define NB_CASTA 2328
#define NB_NORM 100
#define NB_ZERO 57
__global__ __launch_bounds__(256) void prep(
    const float* __restrict__ x, u16* __restrict__ xh, u16* __restrict__ xl,
    const float* __restrict__ ipw, u16* __restrict__ wqT,
    u16* __restrict__ wkvb, const float* __restrict__ ow,
    u16* __restrict__ owb, const float* __restrict__ vals,
    u16* __restrict__ v2b, const float* __restrict__ keys,
    u16* __restrict__ khB, u16* __restrict__ klB) {
  __shared__ char smem[64 * 65 * 2];
  int bid = blockIdx.x;
  const int tid = threadIdx.x;

  if (bid < NB_CASTX) {  // ---- x hi/lo split ----
    const int i = (bid * 256 + tid) * 4;
    const float4 v = *(const float4*)(x + i);
    ushort4 h, l;
    h.x = f2bf(v.x); l.x = f2bf(v.x - bf2f(h.x));
    h.y = f2bf(v.y); l.y = f2bf(v.y - bf2f(h.y));
    h.z = f2bf(v.z); l.z = f2bf(v.z - bf2f(h.z));
    h.w = f2bf(v.w); l.w = f2bf(v.w - bf2f(h.w));
    *(ushort4*)(xh + i) = h;
    *(ushort4*)(xl + i) = l;
    return;
  }
  bid -= NB_CASTX;

  if (bid < NB_TRANS) {  // ---- wq transpose + cast ----
    u16* tile = (u16*)smem;  // [64][65]
    const int bx = bid % 12, by = bid / 12;
    const int tr = tid >> 4, tc = tid & 15;
#pragma unroll
    for (int rr = tr; rr < 64; rr += 16) {
      const float4 v =
          *(const float4*)(ipw + (size_t)(by * 64 + rr) * D_ + bx * 64 + tc * 4);
      tile[rr * 65 + tc * 4 + 0] = f2bf(v.x);
      tile[rr * 65 + tc * 4 + 1] = f2bf(v.y);
      tile[rr * 65 + tc * 4 + 2] = f2bf(v.z);
      tile[rr * 65 + tc * 4 + 3] = f2bf(v.w);
    }
    __syncthreads();
#pragma unroll
    for (int rr = tr; rr < 64; rr += 16) {
      ushort4 o;
      o.x = tile[(tc * 4 + 0) * 65 + rr];
      o.y = tile[(tc * 4 + 1) * 65 + rr];
      o.z = tile[(tc * 4 + 2) * 65 + rr];
      o.w = tile[(tc * 4 + 3) * 65 + rr];
      *(ushort4*)(wqT + (size_t)(bx * 64 + rr) * D_ + by * 64 + tc * 4) = o;
    }
    return;
  }
  bid -= NB_TRANS;

  if (bid < NB_CASTA) {  // ---- plain casts ----
    int i = (bid * 256 + tid) * 4;
    const int n1 = 2 * D_ * D_, n2 = D_ * D_, n3 = P_ * L_ * D_;
    const float* s;
    u16* d;
    if (i < n1) { s = ipw + (size_t)D_ * D_; d = wkvb; }
    else {
      i -= n1;
      if (i < n2) { s = ow; d = owb; }
      else {
        i -= n2;
        if (i >= n3) return;
        s = vals; d = v2b;
      }
    }
    const float4 v = *(const float4*)(s + i);
    ushort4 o;
    o.x = f2bf(v.x); o.y = f2bf(v.y); o.z = f2bf(v.z); o.w = f2bf(v.w);
    *(ushort4*)(d + i) = o;
    return;
  }
  bid -= NB_CASTA;

  if (bid < NB_NORM) {  // ---- normalize keys ----
    float* red = (float*)smem;
    const int p = bid;
    const float* kr = keys + (size_t)p * D_;
    float ss = 0.f;
    for (int d = tid; d < D_; d += 256) { float v = kr[d]; ss += v * v; }
#pragma unroll
    for (int off = 32; off; off >>= 1) ss += __shfl_xor(ss, off);
    if ((tid & 63) == 0) red[tid >> 6] = ss;
    __syncthreads();
    const float tot = red[0] + red[1] + red[2] + red[3];
    const float rinv = 1.0f / fmaxf(sqrtf(tot), 1e-12f);
    for (int d = tid; d < D_; d += 256) {
      const float v = kr[d] * rinv;
      const u16 h = f2bf(v);
      khB[(size_t)p * D_ + d] = h;
      klB[(size_t)p * D_ + d] = f2bf(v - bf2f(h));
    }
    return;
  }
  bid -= NB_NORM;

  {  // ---- zero pads ----
    const int idx = (bid * 256 + tid) * 8;
    const int nv = (MPAD - P_ * L_) * D_;
    const int nk = (PPAD - P_) * D_;
    u16* dst;
    int off;
    if (idx < nv) { dst = v2b + (size_t)P_ * L_ * D_; off = idx; }
    else if (idx < nv + nk) { dst = khB + (size_t)P_ * D_; off = idx - nv; }
    else if (idx < nv + 2 * nk) { dst = klB + (size_t)P_ * D_; off = idx - nv - nk; }
    else return;
    const uint4 z = make_uint4(0u, 0u, 0u, 0u);
    *(uint4*)(dst + off) = z;
  }
}

// ---- gemm_A: kv-proj + 3-term sim screen (2-phase LDS double-buffer) ------
__global__ __launch_bounds__(256) void gemm_A(const u16* __restrict__ xh,
                                              const u16* __restrict__ xl,
                                              const u16* __restrict__ v2b,
                                              const u16* __restrict__ wkvb,
                                              const u16* __restrict__ khB,
                                              const u16* __restrict__ klB,
                                              const float* __restrict__ ipb,
                                              u16* __restrict__ kvK,
                                              u16* __restrict__ vvR,
                                              float* __restrict__ S0,
                                              float* __restrict__ S1,
                                              float* __restrict__ S2) {
  __shared__ u16 As[2][128 * 32];
  __shared__ u16 Ws[2][128 * 32];
  const int tid = threadIdx.x;
  const int wid = tid >> 6, lane = tid & 63;
  const int wr = wid >> 1, wc = wid & 1;

  const u16 *A, *W;
  const float* bias = nullptr;
  float* Sout = nullptr;
  int row0, col0, mode;
  const int bid = blockIdx.x;
  if (bid < 84) {
    A = v2b; W = wkvb; bias = ipb + D_;
    row0 = (bid / 12) * 128; col0 = (bid % 12) * 128;
    mode = (col0 < 768) ? 0 : 1;
  } else {
    const int t = bid - 84;
    const int term = t >> 6, rb = t & 63;
    A = (term == 2) ? xl : xh;
    W = (term == 1) ? klB : khB;
    Sout = (term == 0) ? S0 : (term == 1 ? S1 : S2);
    row0 = rb * 128; col0 = 0; mode = 2;
  }

  f32x4 acc[4][4] = {};
  const u16* aSrc = A + (size_t)(row0 + wid * 16 + (lane >> 2)) * D_ + (lane & 3) * 8;
  const u16* wSrc = W + (size_t)(col0 + wid * 16 + (lane >> 2)) * D_ + (lane & 3) * 8;
  const int dOff = (wid * 16) * 32;

  // prologue: stage k0=0 into buf 0
  gload16(aSrc, &As[0][dOff]);
  gload16(aSrc + (size_t)64 * D_, &As[0][64 * 32 + dOff]);
  gload16(wSrc, &Ws[0][dOff]);
  gload16(wSrc + (size_t)64 * D_, &Ws[0][64 * 32 + dOff]);
  __syncthreads();

  for (int k0 = 0; k0 < D_; k0 += 32) {
    const int cur = (k0 >> 5) & 1;
    if (k0 + 32 < D_) {
      const int nxt = cur ^ 1;
      gload16(aSrc + k0 + 32, &As[nxt][dOff]);
      gload16(aSrc + (size_t)64 * D_ + k0 + 32, &As[nxt][64 * 32 + dOff]);
      gload16(wSrc + k0 + 32, &Ws[nxt][dOff]);
      gload16(wSrc + (size_t)64 * D_ + k0 + 32, &Ws[nxt][64 * 32 + dOff]);
    }
    const int lr = lane & 15, lk = (lane >> 4) * 8;
    bf16x8 af[4], bfr[4];
#pragma unroll
    for (int i = 0; i < 4; ++i) {
      af[i]  = *(const bf16x8*)&As[cur][(wr * 64 + i * 16 + lr) * 32 + lk];
      bfr[i] = *(const bf16x8*)&Ws[cur][(wc * 64 + i * 16 + lr) * 32 + lk];
    }
#pragma unroll
    for (int mi = 0; mi < 4; ++mi)
#pragma unroll
      for (int ni = 0; ni < 4; ++ni)
        acc[mi][ni] = __builtin_amdgcn_mfma_f32_16x16x32_bf16(af[mi], bfr[ni],
                                                              acc[mi][ni], 0, 0, 0);
    __syncthreads();
  }

  const int lr = lane & 15, lg = lane >> 4;
#pragma unroll
  for (int mi = 0; mi < 4; ++mi) {
#pragma unroll
    for (int ni = 0; ni < 4; ++ni) {
      const int ccol = col0 + wc * 64 + ni * 16 + lr;
      const int crow = row0 + wr * 64 + mi * 16 + lg * 4;
      if (mode == 2) {
        *(f32x4*)(&Sout[(size_t)ccol * B_ + crow]) = acc[mi][ni];
      } else {
#pragma unroll
        for (int r = 0; r < 4; ++r) {
          const int rr = crow + r;
          if (mode == 0) {
            kvK[(size_t)rr * D_ + ccol] = f2bf(acc[mi][ni][r] + bias[ccol]);
          } else {
            if (rr < P_ * L_)
              vvR[(size_t)rr * D_ + (ccol - D_)] = f2bf(acc[mi][ni][r] + bias[ccol]);
          }
        }
      }
    }
  }
}

// ---- gemm_B: kq8 = fp8(kvK @ wqT^T), vvO8 = fp8(vvR @ ow^T), sb, sel_topk --
// blocks [0,42): kq8; [42,84): vvO8; [84,308): sb; [308,340): sel_topk
__global__ __launch_bounds__(256) void gemm_B(const u16* __restrict__ kvK,
                                              const u16* __restrict__ wqT,
                                              const u16* __restrict__ vvR,
                                              const u16* __restrict__ owb,
                                              const float* __restrict__ ipb,
                                              const float* __restrict__ S0,
                                              const float* __restrict__ S1,
                                              const float* __restrict__ S2,
                                              u8* __restrict__ kq8,
                                              u8* __restrict__ vvO8,
                                              float* __restrict__ sb,
                                              int* __restrict__ topk) {
  __shared__ u16 As[2][128 * 32];
  __shared__ u16 Ws[2][128 * 32];
  const int tid = threadIdx.x;
  const int wid = tid >> 6, lane = tid & 63;
  const int bid = blockIdx.x;

  if (bid >= 308) {  // ---- sel_topk: lane-per-row top-5 scan ----
    const int b = (bid - 308) * 256 + tid;
    float t[K_];
    int ix[K_];
#pragma unroll
    for (int k = 0; k < K_; ++k) { t[k] = -1e30f; ix[k] = 0; }
#pragma unroll 4
    for (int p = 0; p < P_; ++p) {
      const size_t idx = (size_t)p * B_ + b;
      const float v = S0[idx] + S1[idx] + S2[idx];
      bool g[K_];
#pragma unroll
      for (int k = 0; k < K_; ++k) g[k] = v > t[k];
#pragma unroll
      for (int k = K_ - 1; k >= 1; --k) {
        t[k] = g[k - 1] ? t[k - 1] : (g[k] ? v : t[k]);
        ix[k] = g[k - 1] ? ix[k - 1] : (g[k] ? p : ix[k]);
      }
      t[0] = g[0] ? v : t[0];
      ix[0] = g[0] ? p : ix[0];
    }
#pragma unroll
    for (int k = 0; k < K_; ++k) topk[(size_t)b * K_ + k] = ix[k];
    return;
  }

  if (bid >= 84) {  // ---- sb rows ----
    const int row = (bid - 84) * 4 + wid;
    const u16* kr = kvK + (size_t)row * D_;
    float a = 0.f;
#pragma unroll
    for (int j = 0; j < 12; ++j)
      a += ipb[lane + 64 * j] * bf2f(kr[lane + 64 * j]);
#pragma unroll
    for (int off = 32; off; off >>= 1) a += __shfl_xor(a, off);
    if (lane == 0) sb[row] = a;
    return;
  }

  const int wr = wid >> 1, wc = wid & 1;
  const int t = (bid < 42) ? bid : bid - 42;
  const u16* A = (bid < 42) ? kvK : vvR;
  const u16* W = (bid < 42) ? wqT : owb;
  u8* C = (bid < 42) ? kq8 : vvO8;
  const int row0 = (t / 6) * 128, col0 = (t % 6) * 128;

  f32x4 acc[4][4] = {};
  const u16* aSrc = A + (size_t)(row0 + wid * 16 + (lane >> 2)) * D_ + (lane & 3) * 8;
  const u16* wSrc = W + (size_t)(col0 + wid * 16 + (lane >> 2)) * D_ + (lane & 3) * 8;
  const int dOff = (wid * 16) * 32;

  gload16(aSrc, &As[0][dOff]);
  gload16(aSrc + (size_t)64 * D_, &As[0][64 * 32 + dOff]);
  gload16(wSrc, &Ws[0][dOff]);
  gload16(wSrc + (size_t)64 * D_, &Ws[0][64 * 32 + dOff]);
  __syncthreads();

  for (int k0 = 0; k0 < D_; k0 += 32) {
    const int cur = (k0 >> 5) & 1;
    if (k0 + 32 < D_) {
      const int nxt = cur ^ 1;
      gload16(aSrc + k0 + 32, &As[nxt][dOff]);
      gload16(aSrc + (size_t)64 * D_ + k0 + 32, &As[nxt][64 * 32 + dOff]);
      gload16(wSrc + k0 + 32, &Ws[nxt][dOff]);
      gload16(wSrc + (size_t)64 * D_ + k0 + 32, &Ws[nxt][64 * 32 + dOff]);
    }
    const int lr = lane & 15, lk = (lane >> 4) * 8;
    bf16x8 af[4], bfr[4];
#pragma unroll
    for (int i = 0; i < 4; ++i) {
      af[i]  = *(const bf16x8*)&As[cur][(wr * 64 + i * 16 + lr) * 32 + lk];
      bfr[i] = *(const bf16x8*)&Ws[cur][(wc * 64 + i * 16 + lr) * 32 + lk];
    }
#pragma unroll
    for (int mi = 0; mi < 4; ++mi)
#pragma unroll
      for (int ni = 0; ni < 4; ++ni)
        acc[mi][ni] = __builtin_amdgcn_mfma_f32_16x16x32_bf16(af[mi], bfr[ni],
                                                              acc[mi][ni], 0, 0, 0);
    __syncthreads();
  }

  const int lr = lane & 15, lg = lane >> 4;
#pragma unroll
  for (int mi = 0; mi < 4; ++mi) {
#pragma unroll
    for (int ni = 0; ni < 4; ++ni) {
      const int ccol = col0 + wc * 64 + ni * 16 + lr;
      const int crow = row0 + wr * 64 + mi * 16 + lg * 4;
#pragma unroll
      for (int r = 0; r < 4; ++r)
        C[(size_t)(crow + r) * D_ + ccol] = f2fp8(acc[mi][ni][r]);
    }
  }
}

// ------- fused QK-gather + softmax + gather-PV + residual + LayerNorm -----
// v9: raw LDS-only barriers (no vmcnt drain), PV prefetch across softmax,
// residual from xh+xl (no fp32 x read), separate part[] LDS.
__global__ __launch_bounds__(192) void ctx_ln(
    const u16* __restrict__ xh, const u16* __restrict__ xl,
    const u8* __restrict__ kq8, const float* __restrict__ sb,
    const int* __restrict__ topk, const u8* __restrict__ vvO8,
    const float* __restrict__ ob, const float* __restrict__ gamma,
    const float* __restrict__ beta, float* __restrict__ out) {
  const int b = blockIdx.x, tid = threadIdx.x;
  __shared__ float wS[S_];
  __shared__ int rS[S_];
  __shared__ float pdot[S_ * 25];  // [s*25 + c], stride-25 odd -> conflict-free
  __shared__ float part[768];      // [e*96 + j]
  __shared__ float red[6];
  const float SCALE = 0.07216878364870323f;  // 1/sqrt(192)

  if (tid < S_)
    rS[tid] = topk[(size_t)b * K_ + (tid >> 3)] * L_ + (tid & 7);
  ldsbar();

  const int g = tid / 96;
  const int j = tid % 96;
  const int d0 = j * 8;

  // ---- phase 1: QK partial dots over 20 rows (parity g) ----
  const uint4 xv4 = *(const uint4*)(xh + (size_t)b * D_ + d0);
  const f32x2 x0 = {bflo(xv4.x), bfhi(xv4.x)};
  const f32x2 x1 = {bflo(xv4.y), bfhi(xv4.y)};
  const f32x2 x2 = {bflo(xv4.z), bfhi(xv4.z)};
  const f32x2 x3 = {bflo(xv4.w), bfhi(xv4.w)};

  int roA[10], roB[10];
#pragma unroll
  for (int q = 0; q < 10; ++q) roA[q] = rS[q * 2 + g] * D_ + d0;
#pragma unroll
  for (int q = 0; q < 10; ++q) roB[q] = rS[(10 + q) * 2 + g] * D_ + d0;

  {
    uint2 ka[10], kc[10];
#pragma unroll
    for (int q = 0; q < 10; ++q) ka[q] = *(const uint2*)(kq8 + roA[q]);
#pragma unroll
    for (int q = 0; q < 10; ++q) kc[q] = *(const uint2*)(kq8 + roB[q]);
#pragma unroll
    for (int q = 0; q < 10; ++q) {
      f32x2 a2 = x0 * __builtin_amdgcn_cvt_pk_f32_fp8(ka[q].x, false);
      a2 += x1 * __builtin_amdgcn_cvt_pk_f32_fp8(ka[q].x, true);
      a2 += x2 * __builtin_amdgcn_cvt_pk_f32_fp8(ka[q].y, false);
      a2 += x3 * __builtin_amdgcn_cvt_pk_f32_fp8(ka[q].y, true);
      float a = a2.x + a2.y;
      a += __shfl_xor(a, 1);
      a += __shfl_xor(a, 2);
      if ((j & 3) == 0) pdot[(q * 2 + g) * 25 + (j >> 2)] = a;
    }
#pragma unroll
    for (int q = 0; q < 10; ++q) {
      f32x2 a2 = x0 * __builtin_amdgcn_cvt_pk_f32_fp8(kc[q].x, false);
      a2 += x1 * __builtin_amdgcn_cvt_pk_f32_fp8(kc[q].x, true);
      a2 += x2 * __builtin_amdgcn_cvt_pk_f32_fp8(kc[q].y, false);
      a2 += x3 * __builtin_amdgcn_cvt_pk_f32_fp8(kc[q].y, true);
      float a = a2.x + a2.y;
      a += __shfl_xor(a, 1);
      a += __shfl_xor(a, 2);
      if ((j & 3) == 0) pdot[((10 + q) * 2 + g) * 25 + (j >> 2)] = a;
    }
  }
  // prefetch PV chunk A (in flight across softmax barrier; no vmcnt drain)
  uint2 pva[10];
#pragma unroll
  for (int q = 0; q < 10; ++q) pva[q] = *(const uint2*)(vvO8 + roA[q]);
  ldsbar();

  // ---- phase 2: reduce 24 partials per row + softmax (wave 0) ----
  if (tid < 64) {
    float v = -1e30f;
    if (tid < S_) {
      const float* pr = pdot + tid * 25;
      float a0 = 0.f, a1 = 0.f, a2 = 0.f, a3 = 0.f;
#pragma unroll
      for (int c = 0; c < 24; c += 4) {
        a0 += pr[c]; a1 += pr[c + 1]; a2 += pr[c + 2]; a3 += pr[c + 3];
      }
      v = (a0 + a1 + a2 + a3 + sb[rS[tid]]) * SCALE;
    }
    float m = v;
#pragma unroll
    for (int off = 32; off; off >>= 1) m = fmaxf(m, __shfl_xor(m, off));
    const float e = (tid < S_) ? __expf(v - m) : 0.f;
    float s = e;
#pragma unroll
    for (int off = 32; off; off >>= 1) s += __shfl_xor(s, off);
    if (tid < S_) wS[tid] = e / s;
  }
  ldsbar();

  // ---- phase 3: PV gather (consume prefetched A, prefetch+consume B) ----
  uint2 pvb[10];
#pragma unroll
  for (int q = 0; q < 10; ++q) pvb[q] = *(const uint2*)(vvO8 + roB[q]);
  f32x2 c2[4] = {};
#pragma unroll
  for (int q = 0; q < 10; ++q) {
    const float w = wS[q * 2 + g];
    const f32x2 w2 = {w, w};
    c2[0] += w2 * __builtin_amdgcn_cvt_pk_f32_fp8(pva[q].x, false);
    c2[1] += w2 * __builtin_amdgcn_cvt_pk_f32_fp8(pva[q].x, true);
    c2[2] += w2 * __builtin_amdgcn_cvt_pk_f32_fp8(pva[q].y, false);
    c2[3] += w2 * __builtin_amdgcn_cvt_pk_f32_fp8(pva[q].y, true);
  }
#pragma unroll
  for (int q = 0; q < 10; ++q) {
    const float w = wS[(10 + q) * 2 + g];
    const f32x2 w2 = {w, w};
    c2[0] += w2 * __builtin_amdgcn_cvt_pk_f32_fp8(pvb[q].x, false);
    c2[1] += w2 * __builtin_amdgcn_cvt_pk_f32_fp8(pvb[q].x, true);
    c2[2] += w2 * __builtin_amdgcn_cvt_pk_f32_fp8(pvb[q].y, false);
    c2[3] += w2 * __builtin_amdgcn_cvt_pk_f32_fp8(pvb[q].y, true);
  }
  float c[8] = {c2[0].x, c2[0].y, c2[1].x, c2[1].y,
                c2[2].x, c2[2].y, c2[3].x, c2[3].y};
  if (g == 1) {
#pragma unroll
    for (int e = 0; e < 8; ++e) part[e * 96 + j] = c[e];
  }
  ldsbar();

  // ---- phase 4: residual (from xh regs + xl) + LayerNorm (group 0) ----
  float y[8];
  float s1 = 0.f, s2 = 0.f;
  if (g == 0) {
    const uint4 xlv = *(const uint4*)(xl + (size_t)b * D_ + d0);
    const float4 oa = *(const float4*)(ob + d0);
    const float4 obv = *(const float4*)(ob + d0 + 4);
    const float xr[8] = {x0.x + bflo(xlv.x), x0.y + bfhi(xlv.x),
                         x1.x + bflo(xlv.y), x1.y + bfhi(xlv.y),
                         x2.x + bflo(xlv.z), x2.y + bfhi(xlv.z),
                         x3.x + bflo(xlv.w), x3.y + bfhi(xlv.w)};
    const float orr[8] = {oa.x, oa.y, oa.z, oa.w, obv.x, obv.y, obv.z, obv.w};
#pragma unroll
    for (int e = 0; e < 8; ++e) {
      const float v = xr[e] + c[e] + part[e * 96 + j] + orr[e];
      y[e] = v; s1 += v; s2 += v * v;
    }
  }
#pragma unroll
  for (int off = 32; off; off >>= 1) {
    s1 += __shfl_xor(s1, off);
    s2 += __shfl_xor(s2, off);
  }
  const int wv = tid >> 6;
  if ((tid & 63) == 0) { red[wv] = s1; red[3 + wv] = s2; }
  ldsbar();
  s1 = red[0] + red[1] + red[2];
  s2 = red[3] + red[4] + red[5];
  const float mu = s1 * (1.f / D_);
  const float var = s2 * (1.f / D_) - mu * mu;
  const float rstd = rsqrtf(var + 1e-5f);
  if (g == 0) {
    const float4 ga = *(const float4*)(gamma + d0);
    const float4 gbv = *(const float4*)(gamma + d0 + 4);
    const float4 ba = *(const float4*)(beta + d0);
    const float4 bbv = *(const float4*)(beta + d0 + 4);
    const float gr[8] = {ga.x, ga.y, ga.z, ga.w, gbv.x, gbv.y, gbv.z, gbv.w};
    const float br[8] = {ba.x, ba.y, ba.z, ba.w, bbv.x, bbv.y, bbv.z, bbv.w};
    float4 o1, o2;
    o1.x = (y[0] - mu) * rstd * gr[0] + br[0];
    o1.y = (y[1] - mu) * rstd * gr[1] + br[1];
    o1.z = (y[2] - mu) * rstd * gr[2] + br[2];
    o1.w = (y[3] - mu) * rstd * gr[3] + br[3];
    o2.x = (y[4] - mu) * rstd * gr[4] + br[4];
    o2.y = (y[5] - mu) * rstd * gr[5] + br[5];
    o2.z = (y[6] - mu) * rstd * gr[6] + br[6];
    o2.w = (y[7] - mu) * rstd * gr[7] + br[7];
    *(float4*)(out + (size_t)b * D_ + d0) = o1;
    *(float4*)(out + (size_t)b * D_ + d0 + 4) = o2;
  }
}

extern "C" void kernel_launch(void* const* d_in, const int* in_sizes, int n_in,
                              void* d_out, int out_size, void* d_ws, size_t ws_size,
                              hipStream_t stream) {
  const float* x   = (const float*)d_in[0];
  const float* keys= (const float*)d_in[1];
  const float* vals= (const float*)d_in[2];
  const float* ipw = (const float*)d_in[3];
  const float* ipb = (const float*)d_in[4];
  const float* ow  = (const float*)d_in[5];
  const float* ob  = (const float*)d_in[6];
  const float* lg  = (const float*)d_in[7];
  const float* lb  = (const float*)d_in[8];

  char* ws = (char*)d_ws;
  size_t off = 0;
  auto alloc = [&](size_t bytes) {
    void* p = ws + off;
    off += (bytes + 255) & ~(size_t)255;
    return p;
  };
  u16*   xh   = (u16*)alloc((size_t)B_ * D_ * 2);
  u16*   xl   = (u16*)alloc((size_t)B_ * D_ * 2);
  u16*   wqT  = (u16*)alloc((size_t)D_ * D_ * 2);
  u16*   wkvb = (u16*)alloc((size_t)2 * D_ * D_ * 2);
  u16*   owb  = (u16*)alloc((size_t)D_ * D_ * 2);
  u16*   v2b  = (u16*)alloc((size_t)MPAD * D_ * 2);
  u16*   khB  = (u16*)alloc((size_t)PPAD * D_ * 2);
  u16*   klB  = (u16*)alloc((size_t)PPAD * D_ * 2);
  u16*   kvK  = (u16*)alloc((size_t)MPAD * D_ * 2);
  u16*   vvR  = (u16*)alloc((size_t)MPAD * D_ * 2);
  u8*    vvO8 = (u8*)alloc((size_t)MPAD * D_);
  u8*    kq8  = (u8*)alloc((size_t)MPAD * D_);
  float* S0   = (float*)alloc((size_t)PPAD * B_ * 4);
  float* S1   = (float*)alloc((size_t)PPAD * B_ * 4);
  float* S2   = (float*)alloc((size_t)PPAD * B_ * 4);
  int*   tk   = (int*)alloc((size_t)B_ * K_ * 4);
  float* sb   = (float*)alloc((size_t)MPAD * 4);

  prep<<<NB_CASTX + NB_TRANS + NB_CASTA + NB_NORM + NB_ZERO, 256, 0, stream>>>(
      x, xh, xl, ipw, wqT, wkvb, ow, owb, vals, v2b, keys, khB, klB);

  gemm_A<<<276, 256, 0, stream>>>(xh, xl, v2b, wkvb, khB, klB, ipb,
                                  kvK, vvR, S0, S1, S2);
  gemm_B<<<340, 256, 0, stream>>>(kvK, wqT, vvR, owb, ipb, S0, S1, S2,
                                  kq8, vvO8, sb, tk);
  ctx_ln<<<B_, 192, 0, stream>>>(xh, xl, kq8, sb, tk, vvO8, ob, lg, lb,
                                 (float*)d_out);
}

// Round 2
// 106.010 us; speedup vs baseline: 1.1035x; 1.1035x over previous
//
#include <hip/hip_runtime.h>

#define B_ 8192
#define P_ 100
#define L_ 8
#define D_ 768
#define K_ 5
#define H_ 4
#define HD_ 192
#define S_ 40            // K_*L_
#define MPAD 896         // 800 padded to 7*128 (kv rows / score cols)
#define PPAD 128         // P_ padded

typedef unsigned short u16;
typedef unsigned char u8;
typedef __bf16 bf16x8 __attribute__((ext_vector_type(8)));
typedef float f32x4 __attribute__((ext_vector_type(4)));
typedef float f32x2 __attribute__((ext_vector_type(2)));

__device__ __forceinline__ u16 f2bf(float f) {
  __bf16 h = (__bf16)f;
  return __builtin_bit_cast(unsigned short, h);
}
__device__ __forceinline__ float bf2f(u16 u) {
  unsigned int v = ((unsigned int)u) << 16;
  return __builtin_bit_cast(float, v);
}
__device__ __forceinline__ float bflo(unsigned int u) {
  return __builtin_bit_cast(float, u << 16);
}
__device__ __forceinline__ float bfhi(unsigned int u) {
  return __builtin_bit_cast(float, u & 0xffff0000u);
}
__device__ __forceinline__ u8 f2fp8(float v) {
  const int p = __builtin_amdgcn_cvt_pk_fp8_f32(v, v, 0, false);
  return (u8)(p & 0xff);
}
__device__ __forceinline__ void gload16(const void* g, void* l) {
  __builtin_amdgcn_global_load_lds(
      (const __attribute__((address_space(1))) void*)g,
      (__attribute__((address_space(3))) void*)l, 16, 0, 0);
}

// ================= prep mega-kernel =================
#define NB_CASTX 6144
#define NB_TRANS 144
#define NB_CASTA 2328
#define NB_NORM 100
#define NB_ZERO 57
__global__ __launch_bounds__(256) void prep(
    const float* __restrict__ x, u16* __restrict__ xh, u16* __restrict__ xl,
    const float* __restrict__ ipw, u16* __restrict__ wqT,
    u16* __restrict__ wkvb, const float* __restrict__ ow,
    u16* __restrict__ owb, const float* __restrict__ vals,
    u16* __restrict__ v2b, const float* __restrict__ keys,
    u16* __restrict__ khB, u16* __restrict__ klB) {
  __shared__ char smem[64 * 65 * 2];
  int bid = blockIdx.x;
  const int tid = threadIdx.x;

  if (bid < NB_CASTX) {  // ---- x hi/lo split ----
    const int i = (bid * 256 + tid) * 4;
    const float4 v = *(const float4*)(x + i);
    ushort4 h, l;
    h.x = f2bf(v.x); l.x = f2bf(v.x - bf2f(h.x));
    h.y = f2bf(v.y); l.y = f2bf(v.y - bf2f(h.y));
    h.z = f2bf(v.z); l.z = f2bf(v.z - bf2f(h.z));
    h.w = f2bf(v.w); l.w = f2bf(v.w - bf2f(h.w));
    *(ushort4*)(xh + i) = h;
    *(ushort4*)(xl + i) = l;
    return;
  }
  bid -= NB_CASTX;

  if (bid < NB_TRANS) {  // ---- wq transpose + cast ----
    u16* tile = (u16*)smem;  // [64][65]
    const int bx = bid % 12, by = bid / 12;
    const int tr = tid >> 4, tc = tid & 15;
#pragma unroll
    for (int rr = tr; rr < 64; rr += 16) {
      const float4 v =
          *(const float4*)(ipw + (size_t)(by * 64 + rr) * D_ + bx * 64 + tc * 4);
      tile[rr * 65 + tc * 4 + 0] = f2bf(v.x);
      tile[rr * 65 + tc * 4 + 1] = f2bf(v.y);
      tile[rr * 65 + tc * 4 + 2] = f2bf(v.z);
      tile[rr * 65 + tc * 4 + 3] = f2bf(v.w);
    }
    __syncthreads();
#pragma unroll
    for (int rr = tr; rr < 64; rr += 16) {
      ushort4 o;
      o.x = tile[(tc * 4 + 0) * 65 + rr];
      o.y = tile[(tc * 4 + 1) * 65 + rr];
      o.z = tile[(tc * 4 + 2) * 65 + rr];
      o.w = tile[(tc * 4 + 3) * 65 + rr];
      *(ushort4*)(wqT + (size_t)(bx * 64 + rr) * D_ + by * 64 + tc * 4) = o;
    }
    return;
  }
  bid -= NB_TRANS;

  if (bid < NB_CASTA) {  // ---- plain casts ----
    int i = (bid * 256 + tid) * 4;
    const int n1 = 2 * D_ * D_, n2 = D_ * D_, n3 = P_ * L_ * D_;
    const float* s;
    u16* d;
    if (i < n1) { s = ipw + (size_t)D_ * D_; d = wkvb; }
    else {
      i -= n1;
      if (i < n2) { s = ow; d = owb; }
      else {
        i -= n2;
        if (i >= n3) return;
        s = vals; d = v2b;
      }
    }
    const float4 v = *(const float4*)(s + i);
    ushort4 o;
    o.x = f2bf(v.x); o.y = f2bf(v.y); o.z = f2bf(v.z); o.w = f2bf(v.w);
    *(ushort4*)(d + i) = o;
    return;
  }
  bid -= NB_CASTA;

  if (bid < NB_NORM) {  // ---- normalize keys ----
    float* red = (float*)smem;
    const int p = bid;
    const float* kr = keys + (size_t)p * D_;
    float ss = 0.f;
    for (int d = tid; d < D_; d += 256) { float v = kr[d]; ss += v * v; }
#pragma unroll
    for (int off = 32; off; off >>= 1) ss += __shfl_xor(ss, off);
    if ((tid & 63) == 0) red[tid >> 6] = ss;
    __syncthreads();
    const float tot = red[0] + red[1] + red[2] + red[3];
    const float rinv = 1.0f / fmaxf(sqrtf(tot), 1e-12f);
    for (int d = tid; d < D_; d += 256) {
      const float v = kr[d] * rinv;
      const u16 h = f2bf(v);
      khB[(size_t)p * D_ + d] = h;
      klB[(size_t)p * D_ + d] = f2bf(v - bf2f(h));
    }
    return;
  }
  bid -= NB_NORM;

  {  // ---- zero pads ----
    const int idx = (bid * 256 + tid) * 8;
    const int nv = (MPAD - P_ * L_) * D_;
    const int nk = (PPAD - P_) * D_;
    u16* dst;
    int off;
    if (idx < nv) { dst = v2b + (size_t)P_ * L_ * D_; off = idx; }
    else if (idx < nv + nk) { dst = khB + (size_t)P_ * D_; off = idx - nv; }
    else if (idx < nv + 2 * nk) { dst = klB + (size_t)P_ * D_; off = idx - nv - nk; }
    else return;
    const uint4 z = make_uint4(0u, 0u, 0u, 0u);
    *(uint4*)(dst + off) = z;
  }
}

// ---- gemm_A: kv-proj + 3-term sim screen (2-phase LDS double-buffer) ------
__global__ __launch_bounds__(256) void gemm_A(const u16* __restrict__ xh,
                                              const u16* __restrict__ xl,
                                              const u16* __restrict__ v2b,
                                              const u16* __restrict__ wkvb,
                                              const u16* __restrict__ khB,
                                              const u16* __restrict__ klB,
                                              const float* __restrict__ ipb,
                                              u16* __restrict__ kvK,
                                              u16* __restrict__ vvR,
                                              float* __restrict__ S0,
                                              float* __restrict__ S1,
                                              float* __restrict__ S2) {
  __shared__ u16 As[2][128 * 32];
  __shared__ u16 Ws[2][128 * 32];
  const int tid = threadIdx.x;
  const int wid = tid >> 6, lane = tid & 63;
  const int wr = wid >> 1, wc = wid & 1;

  const u16 *A, *W;
  const float* bias = nullptr;
  float* Sout = nullptr;
  int row0, col0, mode;
  const int bid = blockIdx.x;
  if (bid < 84) {
    A = v2b; W = wkvb; bias = ipb + D_;
    row0 = (bid / 12) * 128; col0 = (bid % 12) * 128;
    mode = (col0 < 768) ? 0 : 1;
  } else {
    const int t = bid - 84;
    const int term = t >> 6, rb = t & 63;
    A = (term == 2) ? xl : xh;
    W = (term == 1) ? klB : khB;
    Sout = (term == 0) ? S0 : (term == 1 ? S1 : S2);
    row0 = rb * 128; col0 = 0; mode = 2;
  }

  f32x4 acc[4][4] = {};
  const u16* aSrc = A + (size_t)(row0 + wid * 16 + (lane >> 2)) * D_ + (lane & 3) * 8;
  const u16* wSrc = W + (size_t)(col0 + wid * 16 + (lane >> 2)) * D_ + (lane & 3) * 8;
  const int dOff = (wid * 16) * 32;

  // prologue: stage k0=0 into buf 0
  gload16(aSrc, &As[0][dOff]);
  gload16(aSrc + (size_t)64 * D_, &As[0][64 * 32 + dOff]);
  gload16(wSrc, &Ws[0][dOff]);
  gload16(wSrc + (size_t)64 * D_, &Ws[0][64 * 32 + dOff]);
  __syncthreads();

  for (int k0 = 0; k0 < D_; k0 += 32) {
    const int cur = (k0 >> 5) & 1;
    if (k0 + 32 < D_) {
      const int nxt = cur ^ 1;
      gload16(aSrc + k0 + 32, &As[nxt][dOff]);
      gload16(aSrc + (size_t)64 * D_ + k0 + 32, &As[nxt][64 * 32 + dOff]);
      gload16(wSrc + k0 + 32, &Ws[nxt][dOff]);
      gload16(wSrc + (size_t)64 * D_ + k0 + 32, &Ws[nxt][64 * 32 + dOff]);
    }
    const int lr = lane & 15, lk = (lane >> 4) * 8;
    bf16x8 af[4], bfr[4];
#pragma unroll
    for (int i = 0; i < 4; ++i) {
      af[i]  = *(const bf16x8*)&As[cur][(wr * 64 + i * 16 + lr) * 32 + lk];
      bfr[i] = *(const bf16x8*)&Ws[cur][(wc * 64 + i * 16 + lr) * 32 + lk];
    }
#pragma unroll
    for (int mi = 0; mi < 4; ++mi)
#pragma unroll
      for (int ni = 0; ni < 4; ++ni)
        acc[mi][ni] = __builtin_amdgcn_mfma_f32_16x16x32_bf16(af[mi], bfr[ni],
                                                              acc[mi][ni], 0, 0, 0);
    __syncthreads();
  }

  const int lr = lane & 15, lg = lane >> 4;
#pragma unroll
  for (int mi = 0; mi < 4; ++mi) {
#pragma unroll
    for (int ni = 0; ni < 4; ++ni) {
      const int ccol = col0 + wc * 64 + ni * 16 + lr;
      const int crow = row0 + wr * 64 + mi * 16 + lg * 4;
      if (mode == 2) {
        *(f32x4*)(&Sout[(size_t)ccol * B_ + crow]) = acc[mi][ni];
      } else {
#pragma unroll
        for (int r = 0; r < 4; ++r) {
          const int rr = crow + r;
          if (mode == 0) {
            kvK[(size_t)rr * D_ + ccol] = f2bf(acc[mi][ni][r] + bias[ccol]);
          } else {
            if (rr < P_ * L_)
              vvR[(size_t)rr * D_ + (ccol - D_)] = f2bf(acc[mi][ni][r] + bias[ccol]);
          }
        }
      }
    }
  }
}

// ---- gemm_B: kq8 = fp8(kvK @ wqT^T), vvO8 = fp8(vvR @ ow^T), sb, sel_topk --
// blocks [0,42): kq8; [42,84): vvO8; [84,308): sb; [308,340): sel_topk
__global__ __launch_bounds__(256) void gemm_B(const u16* __restrict__ kvK,
                                              const u16* __restrict__ wqT,
                                              const u16* __restrict__ vvR,
                                              const u16* __restrict__ owb,
                                              const float* __restrict__ ipb,
                                              const float* __restrict__ S0,
                                              const float* __restrict__ S1,
                                              const float* __restrict__ S2,
                                              u8* __restrict__ kq8,
                                              u8* __restrict__ vvO8,
                                              float* __restrict__ sb,
                                              int* __restrict__ topk) {
  __shared__ u16 As[2][128 * 32];
  __shared__ u16 Ws[2][128 * 32];
  const int tid = threadIdx.x;
  const int wid = tid >> 6, lane = tid & 63;
  const int bid = blockIdx.x;

  if (bid >= 308) {  // ---- sel_topk: lane-per-row top-5 scan ----
    const int b = (bid - 308) * 256 + tid;
    float t[K_];
    int ix[K_];
#pragma unroll
    for (int k = 0; k < K_; ++k) { t[k] = -1e30f; ix[k] = 0; }
#pragma unroll 4
    for (int p = 0; p < P_; ++p) {
      const size_t idx = (size_t)p * B_ + b;
      const float v = S0[idx] + S1[idx] + S2[idx];
      bool g[K_];
#pragma unroll
      for (int k = 0; k < K_; ++k) g[k] = v > t[k];
#pragma unroll
      for (int k = K_ - 1; k >= 1; --k) {
        t[k] = g[k - 1] ? t[k - 1] : (g[k] ? v : t[k]);
        ix[k] = g[k - 1] ? ix[k - 1] : (g[k] ? p : ix[k]);
      }
      t[0] = g[0] ? v : t[0];
      ix[0] = g[0] ? p : ix[0];
    }
#pragma unroll
    for (int k = 0; k < K_; ++k) topk[(size_t)b * K_ + k] = ix[k];
    return;
  }

  if (bid >= 84) {  // ---- sb rows ----
    const int row = (bid - 84) * 4 + wid;
    const u16* kr = kvK + (size_t)row * D_;
    float a = 0.f;
#pragma unroll
    for (int j = 0; j < 12; ++j)
      a += ipb[lane + 64 * j] * bf2f(kr[lane + 64 * j]);
#pragma unroll
    for (int off = 32; off; off >>= 1) a += __shfl_xor(a, off);
    if (lane == 0) sb[row] = a;
    return;
  }

  const int wr = wid >> 1, wc = wid & 1;
  const int t = (bid < 42) ? bid : bid - 42;
  const u16* A = (bid < 42) ? kvK : vvR;
  const u16* W = (bid < 42) ? wqT : owb;
  u8* C = (bid < 42) ? kq8 : vvO8;
  const int row0 = (t / 6) * 128, col0 = (t % 6) * 128;

  f32x4 acc[4][4] = {};
  const u16* aSrc = A + (size_t)(row0 + wid * 16 + (lane >> 2)) * D_ + (lane & 3) * 8;
  const u16* wSrc = W + (size_t)(col0 + wid * 16 + (lane >> 2)) * D_ + (lane & 3) * 8;
  const int dOff = (wid * 16) * 32;

  gload16(aSrc, &As[0][dOff]);
  gload16(aSrc + (size_t)64 * D_, &As[0][64 * 32 + dOff]);
  gload16(wSrc, &Ws[0][dOff]);
  gload16(wSrc + (size_t)64 * D_, &Ws[0][64 * 32 + dOff]);
  __syncthreads();

  for (int k0 = 0; k0 < D_; k0 += 32) {
    const int cur = (k0 >> 5) & 1;
    if (k0 + 32 < D_) {
      const int nxt = cur ^ 1;
      gload16(aSrc + k0 + 32, &As[nxt][dOff]);
      gload16(aSrc + (size_t)64 * D_ + k0 + 32, &As[nxt][64 * 32 + dOff]);
      gload16(wSrc + k0 + 32, &Ws[nxt][dOff]);
      gload16(wSrc + (size_t)64 * D_ + k0 + 32, &Ws[nxt][64 * 32 + dOff]);
    }
    const int lr = lane & 15, lk = (lane >> 4) * 8;
    bf16x8 af[4], bfr[4];
#pragma unroll
    for (int i = 0; i < 4; ++i) {
      af[i]  = *(const bf16x8*)&As[cur][(wr * 64 + i * 16 + lr) * 32 + lk];
      bfr[i] = *(const bf16x8*)&Ws[cur][(wc * 64 + i * 16 + lr) * 32 + lk];
    }
#pragma unroll
    for (int mi = 0; mi < 4; ++mi)
#pragma unroll
      for (int ni = 0; ni < 4; ++ni)
        acc[mi][ni] = __builtin_amdgcn_mfma_f32_16x16x32_bf16(af[mi], bfr[ni],
                                                              acc[mi][ni], 0, 0, 0);
    __syncthreads();
  }

  const int lr = lane & 15, lg = lane >> 4;
#pragma unroll
  for (int mi = 0; mi < 4; ++mi) {
#pragma unroll
    for (int ni = 0; ni < 4; ++ni) {
      const int ccol = col0 + wc * 64 + ni * 16 + lr;
      const int crow = row0 + wr * 64 + mi * 16 + lg * 4;
#pragma unroll
      for (int r = 0; r < 4; ++r)
        C[(size_t)(crow + r) * D_ + ccol] = f2fp8(acc[mi][ni][r]);
    }
  }
}

// ------- fused QK-gather + softmax + gather-PV + residual + LayerNorm -----
// v10: v8 structure (chunked 10-row staging, pooled LDS, __syncthreads,
// low VGPR for occupancy) + residual from xh+xl reload (no fp32 x read).
__global__ __launch_bounds__(192) void ctx_ln(
    const u16* __restrict__ xh, const u16* __restrict__ xl,
    const u8* __restrict__ kq8, const float* __restrict__ sb,
    const int* __restrict__ topk, const u8* __restrict__ vvO8,
    const float* __restrict__ ob, const float* __restrict__ gamma,
    const float* __restrict__ beta, float* __restrict__ out) {
  const int b = blockIdx.x, tid = threadIdx.x;
  __shared__ float wS[S_];
  __shared__ int roS[S_];
  __shared__ float pool[S_ * 25];  // pdot[40][25] (ph1-2) U part[768] (ph3-4)
  __shared__ float red[6];
  float* pdot = pool;              // [s*25 + c], stride-25 odd -> conflict-free
  float* part = pool;              // [e*96 + j]
  const float SCALE = 0.07216878364870323f;  // 1/sqrt(192)

  if (tid < S_)
    roS[tid] = (topk[(size_t)b * K_ + (tid >> 3)] * L_ + (tid & 7)) * D_;
  __syncthreads();

  const int g = tid / 96;
  const int j = tid % 96;
  const int d0 = j * 8;

  // ---- phase 1: QK partial dots, 2 chunks x 10 rows (20 VGPRs staged) ----
  const uint4 xv4 = *(const uint4*)(xh + (size_t)b * D_ + d0);
  const f32x2 x0 = {bflo(xv4.x), bfhi(xv4.x)};
  const f32x2 x1 = {bflo(xv4.y), bfhi(xv4.y)};
  const f32x2 x2 = {bflo(xv4.z), bfhi(xv4.z)};
  const f32x2 x3 = {bflo(xv4.w), bfhi(xv4.w)};
#pragma unroll
  for (int ch = 0; ch < 2; ++ch) {
    uint2 kb[10];
#pragma unroll
    for (int q = 0; q < 10; ++q)
      kb[q] = *(const uint2*)(kq8 + roS[(ch * 10 + q) * 2 + g] + d0);
#pragma unroll
    for (int q = 0; q < 10; ++q) {
      f32x2 a2 = x0 * __builtin_amdgcn_cvt_pk_f32_fp8(kb[q].x, false);
      a2 += x1 * __builtin_amdgcn_cvt_pk_f32_fp8(kb[q].x, true);
      a2 += x2 * __builtin_amdgcn_cvt_pk_f32_fp8(kb[q].y, false);
      a2 += x3 * __builtin_amdgcn_cvt_pk_f32_fp8(kb[q].y, true);
      float a = a2.x + a2.y;
      a += __shfl_xor(a, 1);
      a += __shfl_xor(a, 2);
      if ((j & 3) == 0) pdot[((ch * 10 + q) * 2 + g) * 25 + (j >> 2)] = a;
    }
  }
  __syncthreads();

  // ---- phase 2: reduce 24 partials per row + softmax (wave 0) ----
  if (tid < 64) {
    float v = -1e30f;
    if (tid < S_) {
      const float* pr = pdot + tid * 25;
      float a0 = 0.f, a1 = 0.f, a2 = 0.f, a3 = 0.f;
#pragma unroll
      for (int c = 0; c < 24; c += 4) {
        a0 += pr[c]; a1 += pr[c + 1]; a2 += pr[c + 2]; a3 += pr[c + 3];
      }
      v = (a0 + a1 + a2 + a3 + sb[roS[tid] / D_]) * SCALE;
    }
    float m = v;
#pragma unroll
    for (int off = 32; off; off >>= 1) m = fmaxf(m, __shfl_xor(m, off));
    const float e = (tid < S_) ? __expf(v - m) : 0.f;
    float s = e;
#pragma unroll
    for (int off = 32; off; off >>= 1) s += __shfl_xor(s, off);
    if (tid < S_) wS[tid] = e / s;
  }
  __syncthreads();

  // ---- phase 3: PV gather, 2 chunks x 10 rows ----
  f32x2 c2[4] = {};
#pragma unroll
  for (int ch = 0; ch < 2; ++ch) {
    uint2 pv[10];
#pragma unroll
    for (int q = 0; q < 10; ++q)
      pv[q] = *(const uint2*)(vvO8 + roS[(ch * 10 + q) * 2 + g] + d0);
#pragma unroll
    for (int q = 0; q < 10; ++q) {
      const float w = wS[(ch * 10 + q) * 2 + g];
      const f32x2 w2 = {w, w};
      c2[0] += w2 * __builtin_amdgcn_cvt_pk_f32_fp8(pv[q].x, false);
      c2[1] += w2 * __builtin_amdgcn_cvt_pk_f32_fp8(pv[q].x, true);
      c2[2] += w2 * __builtin_amdgcn_cvt_pk_f32_fp8(pv[q].y, false);
      c2[3] += w2 * __builtin_amdgcn_cvt_pk_f32_fp8(pv[q].y, true);
    }
  }
  float c[8] = {c2[0].x, c2[0].y, c2[1].x, c2[1].y,
                c2[2].x, c2[2].y, c2[3].x, c2[3].y};
  __syncthreads();  // pdot reads done before part overwrites pool
  if (g == 1) {
#pragma unroll
    for (int e = 0; e < 8; ++e) part[e * 96 + j] = c[e];
  }
  __syncthreads();

  // ---- phase 4: residual (xh+xl reload, no fp32 x) + LayerNorm (group 0) --
  float y[8];
  float s1 = 0.f, s2 = 0.f;
  if (g == 0) {
    const uint4 xhv = *(const uint4*)(xh + (size_t)b * D_ + d0);
    const uint4 xlv = *(const uint4*)(xl + (size_t)b * D_ + d0);
    const float4 oa = *(const float4*)(ob + d0);
    const float4 obv = *(const float4*)(ob + d0 + 4);
    const float xr[8] = {bflo(xhv.x) + bflo(xlv.x), bfhi(xhv.x) + bfhi(xlv.x),
                         bflo(xhv.y) + bflo(xlv.y), bfhi(xhv.y) + bfhi(xlv.y),
                         bflo(xhv.z) + bflo(xlv.z), bfhi(xhv.z) + bfhi(xlv.z),
                         bflo(xhv.w) + bflo(xlv.w), bfhi(xhv.w) + bfhi(xlv.w)};
    const float orr[8] = {oa.x, oa.y, oa.z, oa.w, obv.x, obv.y, obv.z, obv.w};
#pragma unroll
    for (int e = 0; e < 8; ++e) {
      const float v = xr[e] + c[e] + part[e * 96 + j] + orr[e];
      y[e] = v; s1 += v; s2 += v * v;
    }
  }
#pragma unroll
  for (int off = 32; off; off >>= 1) {
    s1 += __shfl_xor(s1, off);
    s2 += __shfl_xor(s2, off);
  }
  const int wv = tid >> 6;
  if ((tid & 63) == 0) { red[wv] = s1; red[3 + wv] = s2; }
  __syncthreads();
  s1 = red[0] + red[1] + red[2];
  s2 = red[3] + red[4] + red[5];
  const float mu = s1 * (1.f / D_);
  const float var = s2 * (1.f / D_) - mu * mu;
  const float rstd = rsqrtf(var + 1e-5f);
  if (g == 0) {
    const float4 ga = *(const float4*)(gamma + d0);
    const float4 gbv = *(const float4*)(gamma + d0 + 4);
    const float4 ba = *(const float4*)(beta + d0);
    const float4 bbv = *(const float4*)(beta + d0 + 4);
    const float gr[8] = {ga.x, ga.y, ga.z, ga.w, gbv.x, gbv.y, gbv.z, gbv.w};
    const float br[8] = {ba.x, ba.y, ba.z, ba.w, bbv.x, bbv.y, bbv.z, bbv.w};
    float4 o1, o2;
    o1.x = (y[0] - mu) * rstd * gr[0] + br[0];
    o1.y = (y[1] - mu) * rstd * gr[1] + br[1];
    o1.z = (y[2] - mu) * rstd * gr[2] + br[2];
    o1.w = (y[3] - mu) * rstd * gr[3] + br[3];
    o2.x = (y[4] - mu) * rstd * gr[4] + br[4];
    o2.y = (y[5] - mu) * rstd * gr[5] + br[5];
    o2.z = (y[6] - mu) * rstd * gr[6] + br[6];
    o2.w = (y[7] - mu) * rstd * gr[7] + br[7];
    *(float4*)(out + (size_t)b * D_ + d0) = o1;
    *(float4*)(out + (size_t)b * D_ + d0 + 4) = o2;
  }
}

extern "C" void kernel_launch(void* const* d_in, const int* in_sizes, int n_in,
                              void* d_out, int out_size, void* d_ws, size_t ws_size,
                              hipStream_t stream) {
  const float* x   = (const float*)d_in[0];
  const float* keys= (const float*)d_in[1];
  const float* vals= (const float*)d_in[2];
  const float* ipw = (const float*)d_in[3];
  const float* ipb = (const float*)d_in[4];
  const float* ow  = (const float*)d_in[5];
  const float* ob  = (const float*)d_in[6];
  const float* lg  = (const float*)d_in[7];
  const float* lb  = (const float*)d_in[8];

  char* ws = (char*)d_ws;
  size_t off = 0;
  auto alloc = [&](size_t bytes) {
    void* p = ws + off;
    off += (bytes + 255) & ~(size_t)255;
    return p;
  };
  u16*   xh   = (u16*)alloc((size_t)B_ * D_ * 2);
  u16*   xl   = (u16*)alloc((size_t)B_ * D_ * 2);
  u16*   wqT  = (u16*)alloc((size_t)D_ * D_ * 2);
  u16*   wkvb = (u16*)alloc((size_t)2 * D_ * D_ * 2);
  u16*   owb  = (u16*)alloc((size_t)D_ * D_ * 2);
  u16*   v2b  = (u16*)alloc((size_t)MPAD * D_ * 2);
  u16*   khB  = (u16*)alloc((size_t)PPAD * D_ * 2);
  u16*   klB  = (u16*)alloc((size_t)PPAD * D_ * 2);
  u16*   kvK  = (u16*)alloc((size_t)MPAD * D_ * 2);
  u16*   vvR  = (u16*)alloc((size_t)MPAD * D_ * 2);
  u8*    vvO8 = (u8*)alloc((size_t)MPAD * D_);
  u8*    kq8  = (u8*)alloc((size_t)MPAD * D_);
  float* S0   = (float*)alloc((size_t)PPAD * B_ * 4);
  float* S1   = (float*)alloc((size_t)PPAD * B_ * 4);
  float* S2   = (float*)alloc((size_t)PPAD * B_ * 4);
  int*   tk   = (int*)alloc((size_t)B_ * K_ * 4);
  float* sb   = (float*)alloc((size_t)MPAD * 4);

  prep<<<NB_CASTX + NB_TRANS + NB_CASTA + NB_NORM + NB_ZERO, 256, 0, stream>>>(
      x, xh, xl, ipw, wqT, wkvb, ow, owb, vals, v2b, keys, khB, klB);

  gemm_A<<<276, 256, 0, stream>>>(xh, xl, v2b, wkvb, khB, klB, ipb,
                                  kvK, vvR, S0, S1, S2);
  gemm_B<<<340, 256, 0, stream>>>(kvK, wqT, vvR, owb, ipb, S0, S1, S2,
                                  kq8, vvO8, sb, tk);
  ctx_ln<<<B_, 192, 0, stream>>>(xh, xl, kq8, sb, tk, vvO8, ob, lg, lb,
                                 (float*)d_out);
}

// Round 3
// 105.834 us; speedup vs baseline: 1.1053x; 1.0017x over previous
//
#include <hip/hip_runtime.h>

#define B_ 8192
#define P_ 100
#define L_ 8
#define D_ 768
#define K_ 5
#define H_ 4
#define HD_ 192
#define S_ 40            // K_*L_
#define MPAD 896         // 800 padded to 7*128 (kv rows / score cols)
#define PPAD 128         // P_ padded

typedef unsigned short u16;
typedef unsigned char u8;
typedef __bf16 bf16x8 __attribute__((ext_vector_type(8)));
typedef float f32x4 __attribute__((ext_vector_type(4)));
typedef float f32x2 __attribute__((ext_vector_type(2)));

__device__ __forceinline__ u16 f2bf(float f) {
  __bf16 h = (__bf16)f;
  return __builtin_bit_cast(unsigned short, h);
}
__device__ __forceinline__ float bf2f(u16 u) {
  unsigned int v = ((unsigned int)u) << 16;
  return __builtin_bit_cast(float, v);
}
__device__ __forceinline__ float bflo(unsigned int u) {
  return __builtin_bit_cast(float, u << 16);
}
__device__ __forceinline__ float bfhi(unsigned int u) {
  return __builtin_bit_cast(float, u & 0xffff0000u);
}
__device__ __forceinline__ u8 f2fp8(float v) {
  const int p = __builtin_amdgcn_cvt_pk_fp8_f32(v, v, 0, false);
  return (u8)(p & 0xff);
}
__device__ __forceinline__ void gload16(const void* g, void* l) {
  __builtin_amdgcn_global_load_lds(
      (const __attribute__((address_space(1))) void*)g,
      (__attribute__((address_space(3))) void*)l, 16, 0, 0);
}
__device__ __forceinline__ float qkdot(const uint2 kb, const f32x2 x0,
                                       const f32x2 x1, const f32x2 x2,
                                       const f32x2 x3) {
  f32x2 a2 = x0 * __builtin_amdgcn_cvt_pk_f32_fp8(kb.x, false);
  a2 += x1 * __builtin_amdgcn_cvt_pk_f32_fp8(kb.x, true);
  a2 += x2 * __builtin_amdgcn_cvt_pk_f32_fp8(kb.y, false);
  a2 += x3 * __builtin_amdgcn_cvt_pk_f32_fp8(kb.y, true);
  return a2.x + a2.y;
}
__device__ __forceinline__ void pvacc(f32x2* c2, const uint2 pv, const float w) {
  const f32x2 w2 = {w, w};
  c2[0] += w2 * __builtin_amdgcn_cvt_pk_f32_fp8(pv.x, false);
  c2[1] += w2 * __builtin_amdgcn_cvt_pk_f32_fp8(pv.x, true);
  c2[2] += w2 * __builtin_amdgcn_cvt_pk_f32_fp8(pv.y, false);
  c2[3] += w2 * __builtin_amdgcn_cvt_pk_f32_fp8(pv.y, true);
}

// ================= prep mega-kernel =================
#define NB_CASTX 6144
#define NB_TRANS 144
#define NB_CASTA 2328
#define NB_NORM 100
#define NB_ZERO 57
__global__ __launch_bounds__(256) void prep(
    const float* __restrict__ x, u16* __restrict__ xh, u16* __restrict__ xl,
    const float* __restrict__ ipw, u16* __restrict__ wqT,
    u16* __restrict__ wkvb, const float* __restrict__ ow,
    u16* __restrict__ owb, const float* __restrict__ vals,
    u16* __restrict__ v2b, const float* __restrict__ keys,
    u16* __restrict__ khB, u16* __restrict__ klB) {
  __shared__ char smem[64 * 65 * 2];
  int bid = blockIdx.x;
  const int tid = threadIdx.x;

  if (bid < NB_CASTX) {  // ---- x hi/lo split ----
    const int i = (bid * 256 + tid) * 4;
    const float4 v = *(const float4*)(x + i);
    ushort4 h, l;
    h.x = f2bf(v.x); l.x = f2bf(v.x - bf2f(h.x));
    h.y = f2bf(v.y); l.y = f2bf(v.y - bf2f(h.y));
    h.z = f2bf(v.z); l.z = f2bf(v.z - bf2f(h.z));
    h.w = f2bf(v.w); l.w = f2bf(v.w - bf2f(h.w));
    *(ushort4*)(xh + i) = h;
    *(ushort4*)(xl + i) = l;
    return;
  }
  bid -= NB_CASTX;

  if (bid < NB_TRANS) {  // ---- wq transpose + cast ----
    u16* tile = (u16*)smem;  // [64][65]
    const int bx = bid % 12, by = bid / 12;
    const int tr = tid >> 4, tc = tid & 15;
#pragma unroll
    for (int rr = tr; rr < 64; rr += 16) {
      const float4 v =
          *(const float4*)(ipw + (size_t)(by * 64 + rr) * D_ + bx * 64 + tc * 4);
      tile[rr * 65 + tc * 4 + 0] = f2bf(v.x);
      tile[rr * 65 + tc * 4 + 1] = f2bf(v.y);
      tile[rr * 65 + tc * 4 + 2] = f2bf(v.z);
      tile[rr * 65 + tc * 4 + 3] = f2bf(v.w);
    }
    __syncthreads();
#pragma unroll
    for (int rr = tr; rr < 64; rr += 16) {
      ushort4 o;
      o.x = tile[(tc * 4 + 0) * 65 + rr];
      o.y = tile[(tc * 4 + 1) * 65 + rr];
      o.z = tile[(tc * 4 + 2) * 65 + rr];
      o.w = tile[(tc * 4 + 3) * 65 + rr];
      *(ushort4*)(wqT + (size_t)(bx * 64 + rr) * D_ + by * 64 + tc * 4) = o;
    }
    return;
  }
  bid -= NB_TRANS;

  if (bid < NB_CASTA) {  // ---- plain casts ----
    int i = (bid * 256 + tid) * 4;
    const int n1 = 2 * D_ * D_, n2 = D_ * D_, n3 = P_ * L_ * D_;
    const float* s;
    u16* d;
    if (i < n1) { s = ipw + (size_t)D_ * D_; d = wkvb; }
    else {
      i -= n1;
      if (i < n2) { s = ow; d = owb; }
      else {
        i -= n2;
        if (i >= n3) return;
        s = vals; d = v2b;
      }
    }
    const float4 v = *(const float4*)(s + i);
    ushort4 o;
    o.x = f2bf(v.x); o.y = f2bf(v.y); o.z = f2bf(v.z); o.w = f2bf(v.w);
    *(ushort4*)(d + i) = o;
    return;
  }
  bid -= NB_CASTA;

  if (bid < NB_NORM) {  // ---- normalize keys ----
    float* red = (float*)smem;
    const int p = bid;
    const float* kr = keys + (size_t)p * D_;
    float ss = 0.f;
    for (int d = tid; d < D_; d += 256) { float v = kr[d]; ss += v * v; }
#pragma unroll
    for (int off = 32; off; off >>= 1) ss += __shfl_xor(ss, off);
    if ((tid & 63) == 0) red[tid >> 6] = ss;
    __syncthreads();
    const float tot = red[0] + red[1] + red[2] + red[3];
    const float rinv = 1.0f / fmaxf(sqrtf(tot), 1e-12f);
    for (int d = tid; d < D_; d += 256) {
      const float v = kr[d] * rinv;
      const u16 h = f2bf(v);
      khB[(size_t)p * D_ + d] = h;
      klB[(size_t)p * D_ + d] = f2bf(v - bf2f(h));
    }
    return;
  }
  bid -= NB_NORM;

  {  // ---- zero pads ----
    const int idx = (bid * 256 + tid) * 8;
    const int nv = (MPAD - P_ * L_) * D_;
    const int nk = (PPAD - P_) * D_;
    u16* dst;
    int off;
    if (idx < nv) { dst = v2b + (size_t)P_ * L_ * D_; off = idx; }
    else if (idx < nv + nk) { dst = khB + (size_t)P_ * D_; off = idx - nv; }
    else if (idx < nv + 2 * nk) { dst = klB + (size_t)P_ * D_; off = idx - nv - nk; }
    else return;
    const uint4 z = make_uint4(0u, 0u, 0u, 0u);
    *(uint4*)(dst + off) = z;
  }
}

// ---- gemm_A: kv-proj + 3-term sim screen (2-phase LDS double-buffer) ------
__global__ __launch_bounds__(256) void gemm_A(const u16* __restrict__ xh,
                                              const u16* __restrict__ xl,
                                              const u16* __restrict__ v2b,
                                              const u16* __restrict__ wkvb,
                                              const u16* __restrict__ khB,
                                              const u16* __restrict__ klB,
                                              const float* __restrict__ ipb,
                                              u16* __restrict__ kvK,
                                              u16* __restrict__ vvR,
                                              float* __restrict__ S0,
                                              float* __restrict__ S1,
                                              float* __restrict__ S2) {
  __shared__ u16 As[2][128 * 32];
  __shared__ u16 Ws[2][128 * 32];
  const int tid = threadIdx.x;
  const int wid = tid >> 6, lane = tid & 63;
  const int wr = wid >> 1, wc = wid & 1;

  const u16 *A, *W;
  const float* bias = nullptr;
  float* Sout = nullptr;
  int row0, col0, mode;
  const int bid = blockIdx.x;
  if (bid < 84) {
    A = v2b; W = wkvb; bias = ipb + D_;
    row0 = (bid / 12) * 128; col0 = (bid % 12) * 128;
    mode = (col0 < 768) ? 0 : 1;
  } else {
    const int t = bid - 84;
    const int term = t >> 6, rb = t & 63;
    A = (term == 2) ? xl : xh;
    W = (term == 1) ? klB : khB;
    Sout = (term == 0) ? S0 : (term == 1 ? S1 : S2);
    row0 = rb * 128; col0 = 0; mode = 2;
  }

  f32x4 acc[4][4] = {};
  const u16* aSrc = A + (size_t)(row0 + wid * 16 + (lane >> 2)) * D_ + (lane & 3) * 8;
  const u16* wSrc = W + (size_t)(col0 + wid * 16 + (lane >> 2)) * D_ + (lane & 3) * 8;
  const int dOff = (wid * 16) * 32;

  // prologue: stage k0=0 into buf 0
  gload16(aSrc, &As[0][dOff]);
  gload16(aSrc + (size_t)64 * D_, &As[0][64 * 32 + dOff]);
  gload16(wSrc, &Ws[0][dOff]);
  gload16(wSrc + (size_t)64 * D_, &Ws[0][64 * 32 + dOff]);
  __syncthreads();

  for (int k0 = 0; k0 < D_; k0 += 32) {
    const int cur = (k0 >> 5) & 1;
    if (k0 + 32 < D_) {
      const int nxt = cur ^ 1;
      gload16(aSrc + k0 + 32, &As[nxt][dOff]);
      gload16(aSrc + (size_t)64 * D_ + k0 + 32, &As[nxt][64 * 32 + dOff]);
      gload16(wSrc + k0 + 32, &Ws[nxt][dOff]);
      gload16(wSrc + (size_t)64 * D_ + k0 + 32, &Ws[nxt][64 * 32 + dOff]);
    }
    const int lr = lane & 15, lk = (lane >> 4) * 8;
    bf16x8 af[4], bfr[4];
#pragma unroll
    for (int i = 0; i < 4; ++i) {
      af[i]  = *(const bf16x8*)&As[cur][(wr * 64 + i * 16 + lr) * 32 + lk];
      bfr[i] = *(const bf16x8*)&Ws[cur][(wc * 64 + i * 16 + lr) * 32 + lk];
    }
#pragma unroll
    for (int mi = 0; mi < 4; ++mi)
#pragma unroll
      for (int ni = 0; ni < 4; ++ni)
        acc[mi][ni] = __builtin_amdgcn_mfma_f32_16x16x32_bf16(af[mi], bfr[ni],
                                                              acc[mi][ni], 0, 0, 0);
    __syncthreads();
  }

  const int lr = lane & 15, lg = lane >> 4;
#pragma unroll
  for (int mi = 0; mi < 4; ++mi) {
#pragma unroll
    for (int ni = 0; ni < 4; ++ni) {
      const int ccol = col0 + wc * 64 + ni * 16 + lr;
      const int crow = row0 + wr * 64 + mi * 16 + lg * 4;
      if (mode == 2) {
        *(f32x4*)(&Sout[(size_t)ccol * B_ + crow]) = acc[mi][ni];
      } else {
#pragma unroll
        for (int r = 0; r < 4; ++r) {
          const int rr = crow + r;
          if (mode == 0) {
            kvK[(size_t)rr * D_ + ccol] = f2bf(acc[mi][ni][r] + bias[ccol]);
          } else {
            if (rr < P_ * L_)
              vvR[(size_t)rr * D_ + (ccol - D_)] = f2bf(acc[mi][ni][r] + bias[ccol]);
          }
        }
      }
    }
  }
}

// ---- gemm_B: kq8 = fp8(kvK @ wqT^T), vvO8 = fp8(vvR @ ow^T), sb, sel_topk --
// blocks [0,42): kq8; [42,84): vvO8; [84,308): sb; [308,340): sel_topk
__global__ __launch_bounds__(256) void gemm_B(const u16* __restrict__ kvK,
                                              const u16* __restrict__ wqT,
                                              const u16* __restrict__ vvR,
                                              const u16* __restrict__ owb,
                                              const float* __restrict__ ipb,
                                              const float* __restrict__ S0,
                                              const float* __restrict__ S1,
                                              const float* __restrict__ S2,
                                              u8* __restrict__ kq8,
                                              u8* __restrict__ vvO8,
                                              float* __restrict__ sb,
                                              int* __restrict__ topk) {
  __shared__ u16 As[2][128 * 32];
  __shared__ u16 Ws[2][128 * 32];
  const int tid = threadIdx.x;
  const int wid = tid >> 6, lane = tid & 63;
  const int bid = blockIdx.x;

  if (bid >= 308) {  // ---- sel_topk: lane-per-row top-5 scan ----
    const int b = (bid - 308) * 256 + tid;
    float t[K_];
    int ix[K_];
#pragma unroll
    for (int k = 0; k < K_; ++k) { t[k] = -1e30f; ix[k] = 0; }
#pragma unroll 4
    for (int p = 0; p < P_; ++p) {
      const size_t idx = (size_t)p * B_ + b;
      const float v = S0[idx] + S1[idx] + S2[idx];
      bool g[K_];
#pragma unroll
      for (int k = 0; k < K_; ++k) g[k] = v > t[k];
#pragma unroll
      for (int k = K_ - 1; k >= 1; --k) {
        t[k] = g[k - 1] ? t[k - 1] : (g[k] ? v : t[k]);
        ix[k] = g[k - 1] ? ix[k - 1] : (g[k] ? p : ix[k]);
      }
      t[0] = g[0] ? v : t[0];
      ix[0] = g[0] ? p : ix[0];
    }
#pragma unroll
    for (int k = 0; k < K_; ++k) topk[(size_t)b * K_ + k] = ix[k];
    return;
  }

  if (bid >= 84) {  // ---- sb rows ----
    const int row = (bid - 84) * 4 + wid;
    const u16* kr = kvK + (size_t)row * D_;
    float a = 0.f;
#pragma unroll
    for (int j = 0; j < 12; ++j)
      a += ipb[lane + 64 * j] * bf2f(kr[lane + 64 * j]);
#pragma unroll
    for (int off = 32; off; off >>= 1) a += __shfl_xor(a, off);
    if (lane == 0) sb[row] = a;
    return;
  }

  const int wr = wid >> 1, wc = wid & 1;
  const int t = (bid < 42) ? bid : bid - 42;
  const u16* A = (bid < 42) ? kvK : vvR;
  const u16* W = (bid < 42) ? wqT : owb;
  u8* C = (bid < 42) ? kq8 : vvO8;
  const int row0 = (t / 6) * 128, col0 = (t % 6) * 128;

  f32x4 acc[4][4] = {};
  const u16* aSrc = A + (size_t)(row0 + wid * 16 + (lane >> 2)) * D_ + (lane & 3) * 8;
  const u16* wSrc = W + (size_t)(col0 + wid * 16 + (lane >> 2)) * D_ + (lane & 3) * 8;
  const int dOff = (wid * 16) * 32;

  gload16(aSrc, &As[0][dOff]);
  gload16(aSrc + (size_t)64 * D_, &As[0][64 * 32 + dOff]);
  gload16(wSrc, &Ws[0][dOff]);
  gload16(wSrc + (size_t)64 * D_, &Ws[0][64 * 32 + dOff]);
  __syncthreads();

  for (int k0 = 0; k0 < D_; k0 += 32) {
    const int cur = (k0 >> 5) & 1;
    if (k0 + 32 < D_) {
      const int nxt = cur ^ 1;
      gload16(aSrc + k0 + 32, &As[nxt][dOff]);
      gload16(aSrc + (size_t)64 * D_ + k0 + 32, &As[nxt][64 * 32 + dOff]);
      gload16(wSrc + k0 + 32, &Ws[nxt][dOff]);
      gload16(wSrc + (size_t)64 * D_ + k0 + 32, &Ws[nxt][64 * 32 + dOff]);
    }
    const int lr = lane & 15, lk = (lane >> 4) * 8;
    bf16x8 af[4], bfr[4];
#pragma unroll
    for (int i = 0; i < 4; ++i) {
      af[i]  = *(const bf16x8*)&As[cur][(wr * 64 + i * 16 + lr) * 32 + lk];
      bfr[i] = *(const bf16x8*)&Ws[cur][(wc * 64 + i * 16 + lr) * 32 + lk];
    }
#pragma unroll
    for (int mi = 0; mi < 4; ++mi)
#pragma unroll
      for (int ni = 0; ni < 4; ++ni)
        acc[mi][ni] = __builtin_amdgcn_mfma_f32_16x16x32_bf16(af[mi], bfr[ni],
                                                              acc[mi][ni], 0, 0, 0);
    __syncthreads();
  }

  const int lr = lane & 15, lg = lane >> 4;
#pragma unroll
  for (int mi = 0; mi < 4; ++mi) {
#pragma unroll
    for (int ni = 0; ni < 4; ++ni) {
      const int ccol = col0 + wc * 64 + ni * 16 + lr;
      const int crow = row0 + wr * 64 + mi * 16 + lg * 4;
#pragma unroll
      for (int r = 0; r < 4; ++r)
        C[(size_t)(crow + r) * D_ + ccol] = f2fp8(acc[mi][ni][r]);
    }
  }
}

// ------- fused QK-gather + softmax + gather-PV + residual + LayerNorm -----
// v11: 2 batch rows per block. Softmax parallel on waves 0/1 (one per b),
// phase-4 LN full-width (g0->b0, g1->b1, width-32 reductions), 5 barriers
// per 2 b's. Staging stays at 10-row chunks (low VGPR, occupancy first).
__global__ __launch_bounds__(192) void ctx_ln(
    const u16* __restrict__ xh, const u16* __restrict__ xl,
    const u8* __restrict__ kq8, const float* __restrict__ sb,
    const int* __restrict__ topk, const u8* __restrict__ vvO8,
    const float* __restrict__ ob, const float* __restrict__ gamma,
    const float* __restrict__ beta, float* __restrict__ out) {
  const int b0 = blockIdx.x * 2, tid = threadIdx.x;
  __shared__ float wS[2 * S_];
  __shared__ int roS[2 * S_];     // row * D_
  __shared__ int riS[2 * S_];     // row index (for sb)
  __shared__ float pool[2 * S_ * 25];  // pdot[2][40][25] U part0/part1[768]
  __shared__ float red2[12];
  float* part0 = pool;
  float* part1 = pool + 768;
  const float SCALE = 0.07216878364870323f;  // 1/sqrt(192)

  if (tid < 2 * S_) {
    const int bb = tid >= S_ ? 1 : 0;
    const int s = tid - bb * S_;
    const int ri = topk[(size_t)(b0 + bb) * K_ + (s >> 3)] * L_ + (s & 7);
    riS[tid] = ri;
    roS[tid] = ri * D_;
  }
  __syncthreads();

  const int g = tid / 96;
  const int j = tid % 96;
  const int d0 = j * 8;

  // ---- phase 1: QK partial dots, per b: 2 chunks x 10 rows (parity g) ----
  const uint4 xa4 = *(const uint4*)(xh + (size_t)b0 * D_ + d0);
  const uint4 xb4 = *(const uint4*)(xh + (size_t)(b0 + 1) * D_ + d0);
  const f32x2 xa0 = {bflo(xa4.x), bfhi(xa4.x)};
  const f32x2 xa1 = {bflo(xa4.y), bfhi(xa4.y)};
  const f32x2 xa2 = {bflo(xa4.z), bfhi(xa4.z)};
  const f32x2 xa3 = {bflo(xa4.w), bfhi(xa4.w)};
  const f32x2 xb0 = {bflo(xb4.x), bfhi(xb4.x)};
  const f32x2 xb1 = {bflo(xb4.y), bfhi(xb4.y)};
  const f32x2 xb2 = {bflo(xb4.z), bfhi(xb4.z)};
  const f32x2 xb3 = {bflo(xb4.w), bfhi(xb4.w)};

#pragma unroll
  for (int ch = 0; ch < 2; ++ch) {  // b0
    uint2 kb[10];
#pragma unroll
    for (int q = 0; q < 10; ++q)
      kb[q] = *(const uint2*)(kq8 + roS[(ch * 10 + q) * 2 + g] + d0);
#pragma unroll
    for (int q = 0; q < 10; ++q) {
      float a = qkdot(kb[q], xa0, xa1, xa2, xa3);
      a += __shfl_xor(a, 1);
      a += __shfl_xor(a, 2);
      if ((j & 3) == 0) pool[((ch * 10 + q) * 2 + g) * 25 + (j >> 2)] = a;
    }
  }
#pragma unroll
  for (int ch = 0; ch < 2; ++ch) {  // b1
    uint2 kb[10];
#pragma unroll
    for (int q = 0; q < 10; ++q)
      kb[q] = *(const uint2*)(kq8 + roS[S_ + (ch * 10 + q) * 2 + g] + d0);
#pragma unroll
    for (int q = 0; q < 10; ++q) {
      float a = qkdot(kb[q], xb0, xb1, xb2, xb3);
      a += __shfl_xor(a, 1);
      a += __shfl_xor(a, 2);
      if ((j & 3) == 0) pool[(S_ + (ch * 10 + q) * 2 + g) * 25 + (j >> 2)] = a;
    }
  }
  __syncthreads();

  // ---- phase 2: softmax — wave 0 does b0, wave 1 does b1 ----
  if (tid < 128) {
    const int bb = tid >> 6, lane = tid & 63;
    float v = -1e30f;
    if (lane < S_) {
      const float* pr = pool + (bb * S_ + lane) * 25;
      float a0 = 0.f, a1 = 0.f, a2 = 0.f, a3 = 0.f;
#pragma unroll
      for (int c = 0; c < 24; c += 4) {
        a0 += pr[c]; a1 += pr[c + 1]; a2 += pr[c + 2]; a3 += pr[c + 3];
      }
      v = (a0 + a1 + a2 + a3 + sb[riS[bb * S_ + lane]]) * SCALE;
    }
    float m = v;
#pragma unroll
    for (int off = 32; off; off >>= 1) m = fmaxf(m, __shfl_xor(m, off));
    const float e = (lane < S_) ? __expf(v - m) : 0.f;
    float s = e;
#pragma unroll
    for (int off = 32; off; off >>= 1) s += __shfl_xor(s, off);
    if (lane < S_) wS[bb * S_ + lane] = e / s;
  }
  __syncthreads();

  // ---- phase 3: PV gather for both b's (parity-g rows) ----
  f32x2 ca[4] = {};
#pragma unroll
  for (int ch = 0; ch < 2; ++ch) {  // b0
    uint2 pv[10];
#pragma unroll
    for (int q = 0; q < 10; ++q)
      pv[q] = *(const uint2*)(vvO8 + roS[(ch * 10 + q) * 2 + g] + d0);
#pragma unroll
    for (int q = 0; q < 10; ++q)
      pvacc(ca, pv[q], wS[(ch * 10 + q) * 2 + g]);
  }
  f32x2 cb[4] = {};
#pragma unroll
  for (int ch = 0; ch < 2; ++ch) {  // b1
    uint2 pv[10];
#pragma unroll
    for (int q = 0; q < 10; ++q)
      pv[q] = *(const uint2*)(vvO8 + roS[S_ + (ch * 10 + q) * 2 + g] + d0);
#pragma unroll
    for (int q = 0; q < 10; ++q)
      pvacc(cb, pv[q], wS[S_ + (ch * 10 + q) * 2 + g]);
  }
  const float cva[8] = {ca[0].x, ca[0].y, ca[1].x, ca[1].y,
                        ca[2].x, ca[2].y, ca[3].x, ca[3].y};
  const float cvb[8] = {cb[0].x, cb[0].y, cb[1].x, cb[1].y,
                        cb[2].x, cb[2].y, cb[3].x, cb[3].y};
  // pool's pdot reads finished in phase 2 (before that barrier); safe to
  // overwrite as part0/part1 now.
  if (g == 1) {
#pragma unroll
    for (int e = 0; e < 8; ++e) part0[e * 96 + j] = cva[e];
  } else {
#pragma unroll
    for (int e = 0; e < 8; ++e) part1[e * 96 + j] = cvb[e];
  }
  __syncthreads();

  // ---- phase 4: residual + LN. g0 -> b0, g1 -> b1 (width-32 reduce) ----
  const size_t brow = (size_t)(b0 + g) * D_;
  float y[8];
  float s1 = 0.f, s2 = 0.f;
  {
    const uint4 xlv = *(const uint4*)(xl + brow + d0);
    const float4 oa = *(const float4*)(ob + d0);
    const float4 obv = *(const float4*)(ob + d0 + 4);
    const float orr[8] = {oa.x, oa.y, oa.z, oa.w, obv.x, obv.y, obv.z, obv.w};
    float xr[8];
    if (g == 0) {
      xr[0] = xa0.x; xr[1] = xa0.y; xr[2] = xa1.x; xr[3] = xa1.y;
      xr[4] = xa2.x; xr[5] = xa2.y; xr[6] = xa3.x; xr[7] = xa3.y;
    } else {
      xr[0] = xb0.x; xr[1] = xb0.y; xr[2] = xb1.x; xr[3] = xb1.y;
      xr[4] = xb2.x; xr[5] = xb2.y; xr[6] = xb3.x; xr[7] = xb3.y;
    }
    const float xlr[8] = {bflo(xlv.x), bfhi(xlv.x), bflo(xlv.y), bfhi(xlv.y),
                          bflo(xlv.z), bfhi(xlv.z), bflo(xlv.w), bfhi(xlv.w)};
    const float* cown = (g == 0) ? cva : cvb;
    const float* poth = (g == 0) ? part0 : part1;
#pragma unroll
    for (int e = 0; e < 8; ++e) {
      const float v = (xr[e] + xlr[e]) + cown[e] + poth[e * 96 + j] + orr[e];
      y[e] = v; s1 += v; s2 += v * v;
    }
  }
#pragma unroll
  for (int off = 16; off; off >>= 1) {
    s1 += __shfl_xor(s1, off, 32);
    s2 += __shfl_xor(s2, off, 32);
  }
  const int hw = tid >> 5;  // 6 half-waves; hw 0-2 -> g0, hw 3-5 -> g1
  if ((tid & 31) == 0) { red2[hw] = s1; red2[6 + hw] = s2; }
  __syncthreads();
  const int hb = g * 3;
  s1 = red2[hb] + red2[hb + 1] + red2[hb + 2];
  s2 = red2[6 + hb] + red2[6 + hb + 1] + red2[6 + hb + 2];
  const float mu = s1 * (1.f / D_);
  const float var = s2 * (1.f / D_) - mu * mu;
  const float rstd = rsqrtf(var + 1e-5f);
  {
    const float4 ga = *(const float4*)(gamma + d0);
    const float4 gbv = *(const float4*)(gamma + d0 + 4);
    const float4 ba = *(const float4*)(beta + d0);
    const float4 bbv = *(const float4*)(beta + d0 + 4);
    const float gr[8] = {ga.x, ga.y, ga.z, ga.w, gbv.x, gbv.y, gbv.z, gbv.w};
    const float br[8] = {ba.x, ba.y, ba.z, ba.w, bbv.x, bbv.y, bbv.z, bbv.w};
    float4 o1, o2;
    o1.x = (y[0] - mu) * rstd * gr[0] + br[0];
    o1.y = (y[1] - mu) * rstd * gr[1] + br[1];
    o1.z = (y[2] - mu) * rstd * gr[2] + br[2];
    o1.w = (y[3] - mu) * rstd * gr[3] + br[3];
    o2.x = (y[4] - mu) * rstd * gr[4] + br[4];
    o2.y = (y[5] - mu) * rstd * gr[5] + br[5];
    o2.z = (y[6] - mu) * rstd * gr[6] + br[6];
    o2.w = (y[7] - mu) * rstd * gr[7] + br[7];
    *(float4*)(out + brow + d0) = o1;
    *(float4*)(out + brow + d0 + 4) = o2;
  }
}

extern "C" void kernel_launch(void* const* d_in, const int* in_sizes, int n_in,
                              void* d_out, int out_size, void* d_ws, size_t ws_size,
                              hipStream_t stream) {
  const float* x   = (const float*)d_in[0];
  const float* keys= (const float*)d_in[1];
  const float* vals= (const float*)d_in[2];
  const float* ipw = (const float*)d_in[3];
  const float* ipb = (const float*)d_in[4];
  const float* ow  = (const float*)d_in[5];
  const float* ob  = (const float*)d_in[6];
  const float* lg  = (const float*)d_in[7];
  const float* lb  = (const float*)d_in[8];

  char* ws = (char*)d_ws;
  size_t off = 0;
  auto alloc = [&](size_t bytes) {
    void* p = ws + off;
    off += (bytes + 255) & ~(size_t)255;
    return p;
  };
  u16*   xh   = (u16*)alloc((size_t)B_ * D_ * 2);
  u16*   xl   = (u16*)alloc((size_t)B_ * D_ * 2);
  u16*   wqT  = (u16*)alloc((size_t)D_ * D_ * 2);
  u16*   wkvb = (u16*)alloc((size_t)2 * D_ * D_ * 2);
  u16*   owb  = (u16*)alloc((size_t)D_ * D_ * 2);
  u16*   v2b  = (u16*)alloc((size_t)MPAD * D_ * 2);
  u16*   khB  = (u16*)alloc((size_t)PPAD * D_ * 2);
  u16*   klB  = (u16*)alloc((size_t)PPAD * D_ * 2);
  u16*   kvK  = (u16*)alloc((size_t)MPAD * D_ * 2);
  u16*   vvR  = (u16*)alloc((size_t)MPAD * D_ * 2);
  u8*    vvO8 = (u8*)alloc((size_t)MPAD * D_);
  u8*    kq8  = (u8*)alloc((size_t)MPAD * D_);
  float* S0   = (float*)alloc((size_t)PPAD * B_ * 4);
  float* S1   = (float*)alloc((size_t)PPAD * B_ * 4);
  float* S2   = (float*)alloc((size_t)PPAD * B_ * 4);
  int*   tk   = (int*)alloc((size_t)B_ * K_ * 4);
  float* sb   = (float*)alloc((size_t)MPAD * 4);

  prep<<<NB_CASTX + NB_TRANS + NB_CASTA + NB_NORM + NB_ZERO, 256, 0, stream>>>(
      x, xh, xl, ipw, wqT, wkvb, ow, owb, vals, v2b, keys, khB, klB);

  gemm_A<<<276, 256, 0, stream>>>(xh, xl, v2b, wkvb, khB, klB, ipb,
                                  kvK, vvR, S0, S1, S2);
  gemm_B<<<340, 256, 0, stream>>>(kvK, wqT, vvR, owb, ipb, S0, S1, S2,
                                  kq8, vvO8, sb, tk);
  ctx_ln<<<B_ / 2, 192, 0, stream>>>(xh, xl, kq8, sb, tk, vvO8, ob, lg, lb,
                                     (float*)d_out);
}